// Round 8
// baseline (469.168 us; speedup 1.0000x reference)
//
#include <hip/hip_runtime.h>
#include <hip/hip_bf16.h>

constexpr int V = 128;
constexpr int RED_BLOCKS = 2048;  // reduce partition (bit-exact x8 -> DO NOT CHANGE)

// 16B vector type usable with __builtin_nontemporal_load.
typedef float __attribute__((ext_vector_type(4))) f4_t;
__device__ __forceinline__ f4_t ldnt(const float* p) {
  return __builtin_nontemporal_load((const f4_t*)p);
}

// ---------------- Kernel 1: partial[b][8] = chunk of coords_flat @ W0 ----------------
// Also zeroes vol (8 MB) in its prologue: the store hides under the 108 MB
// W0/inds fetch. Summation partition kept bit-identical to the verified
// baseline (absmax pinned; do not perturb x8 rounding). Grid MUST stay 2048.
__global__ __launch_bounds__(256) void k_reduce_w0(
    const int* __restrict__ inds, const float* __restrict__ W0,
    float* __restrict__ partials, float4* __restrict__ vol4, int threeN) {
  int g = blockIdx.x * 256 + threadIdx.x;
  // zero vol: 2M floats = 524288 float4, grid is exactly 2048*256 = 524288
  vol4[g] = make_float4(0.f, 0.f, 0.f, 0.f);

  float acc[8];
#pragma unroll
  for (int k = 0; k < 8; ++k) acc[k] = 0.f;

  int stride = gridDim.x * blockDim.x;
  for (int j = g; j < threeN; j += stride) {
    int c = j % 3;
    float cval = ((float)inds[j + 2 - 2 * c] - 64.0f) * 0.015625f;
    const float* w = W0 + (size_t)j * 8;
    f4_t a = ldnt(w);      // streaming, read-once: keep out of L2
    f4_t b = ldnt(w + 4);
    acc[0] += cval * a.x; acc[1] += cval * a.y;
    acc[2] += cval * a.z; acc[3] += cval * a.w;
    acc[4] += cval * b.x; acc[5] += cval * b.y;
    acc[6] += cval * b.z; acc[7] += cval * b.w;
  }

#pragma unroll
  for (int off = 32; off > 0; off >>= 1) {
#pragma unroll
    for (int k = 0; k < 8; ++k) acc[k] += __shfl_down(acc[k], off);
  }

  __shared__ float red[4][8];
  int wave = threadIdx.x >> 6;
  int lane = threadIdx.x & 63;
  if (lane == 0) {
#pragma unroll
    for (int k = 0; k < 8; ++k) red[wave][k] = acc[k];
  }
  __syncthreads();
  if (threadIdx.x < 8) {
    int k = threadIdx.x;
    partials[(size_t)blockIdx.x * 8 + k] = red[0][k] + red[1][k] + red[2][k] + red[3][k];
  }
}

// ---------------- Kernel 2: reduce partials + tiny MLP (R7-verified) ----------------
// 8-lane parallel MLP: lane kk owns element kk; per-element FMA order
// (j ascending) and x += sinf(t) are expression-identical to the serial
// version -> x8 is BIT-EXACT. Serial depth 5 sinf instead of ~40.
__global__ __launch_bounds__(256) void k_mlp(
    const float* __restrict__ partials, int nb,
    const float* __restrict__ b0,
    const float* __restrict__ W1, const float* __restrict__ b1,
    const float* __restrict__ W2, const float* __restrict__ b2,
    const float* __restrict__ W3, const float* __restrict__ b3,
    const float* __restrict__ W4, const float* __restrict__ b4,
    float* __restrict__ x8_out) {
  __shared__ float red[256];
  __shared__ float accv[8];
  __shared__ float xs[8];
  int tid = threadIdx.x;
  int k = tid & 7;
  float s = 0.f;
  for (int b = tid >> 3; b < nb; b += 32) s += partials[(size_t)b * 8 + k];
  red[tid] = s;
  __syncthreads();
  if (tid < 8) {
    float t = 0.f;
    for (int j = tid; j < 256; j += 8) t += red[j];
    accv[tid] = t;
  }
  __syncthreads();
  if (tid < 8) xs[tid] = sinf(accv[tid] + b0[tid]);
  __syncthreads();
  const float* Ws[4] = {W1, W2, W3, W4};
  const float* bs[4] = {b1, b2, b3, b4};
  for (int l = 0; l < 4; ++l) {
    float xn = 0.f;
    if (tid < 8) {
      float xj[8];
#pragma unroll
      for (int j = 0; j < 8; ++j) xj[j] = xs[j];
      float ss = bs[l][tid];
#pragma unroll
      for (int j = 0; j < 8; ++j) ss += xj[j] * Ws[l][j * 8 + tid];
      xn = xs[tid] + sinf(ss);
    }
    __syncthreads();
    if (tid < 8) xs[tid] = xn;
    __syncthreads();
  }
  if (tid < 8) x8_out[tid] = xs[tid];
}

__device__ inline void scatter_direct(float* vol, float cx, float cy, float cz,
                                      float value) {
  float bxf = floorf(cx), byf = floorf(cy), bzf = floorf(cz);
  int bx = (int)bxf, by = (int)byf, bz = (int)bzf;
  float fx = cx - bxf, fy = cy - byf, fz = cz - bzf;
  float gx = 1.f - fx, gy = 1.f - fy, gz = 1.f - fz;
#pragma unroll
  for (int dz = 0; dz < 2; ++dz)
#pragma unroll
    for (int dy = 0; dy < 2; ++dy)
#pragma unroll
      for (int dx = 0; dx < 2; ++dx) {
        float w = value * (dx ? fx : gx) * (dy ? fy : gy) * (dz ? fz : gz);
        int px = bx + dx, py = by + dy, pz = bz + dz;
        if (px < 0) px += V;   // JAX negative-index wrap
        if (py < 0) py += V;
        if (pz < 0) pz += V;
        if ((unsigned)px < (unsigned)V && (unsigned)py < (unsigned)V &&
            (unsigned)pz < (unsigned)V)
          atomicAdd(vol + ((size_t)pz * V * V + (size_t)py * V + px), w);
      }
}

// ---------------- Kernel 3: decode + DIRECT fire-and-forget scatter ----------------
// Bucketing ablation (R8 experiment): replaces k_decode_scatter + k_tile_fused.
// Per point: 8 no-return global atomicAdds (issue-and-proceed; wave never waits)
// into L2-resident vol. Deletes: cnt atomics + pos-dependent srt stores (the
// latency chain), 16MB srt write + 16MB re-read, 8M LDS atomics, 2.2M writeback
// atomics, cnt zeroing, and one dispatch boundary. Decode math is R7-verbatim;
// only the accumulation ORDER into vol changes (atomic reordering — proven
// threshold-safe across R0-R7, absmax invariant at 0.015625).
__global__ __launch_bounds__(256) void k_scatter(
    const int* __restrict__ inds, const float* __restrict__ refv,
    const float* __restrict__ W5, const float* __restrict__ b5,
    const float* __restrict__ x8_buf, float* __restrict__ vol, int N) {
  __shared__ float x8[8];
  if (threadIdx.x < 8) x8[threadIdx.x] = x8_buf[threadIdx.x];
  __syncthreads();

  int i = blockIdx.x * 256 + threadIdx.x;
  if (i >= N) return;

  const size_t fourN = (size_t)4 * N;
  f4_t o = ldnt(b5 + (size_t)4 * i);  // streaming weights: non-temporal,
  float out0 = o.x, out1 = o.y, out2 = o.z, out3 = o.w;
#pragma unroll
  for (int k = 0; k < 8; ++k) {
    float xv = x8[k];
    f4_t w = ldnt(W5 + (size_t)k * fourN + (size_t)4 * i);  // keep L2 for vol
    out0 += xv * w.x; out1 += xv * w.y; out2 += xv * w.z; out3 += xv * w.w;
  }
  float value = refv[i] + out3;
  value = value > 0.f ? value : 0.f;
  if (value <= 0.f) return;  // zero value contributes nothing (~50% of points)

  int i0 = inds[3 * i], i1 = inds[3 * i + 1], i2 = inds[3 * i + 2];
  float cx = (((float)i2 - 64.0f) * 0.015625f + out0) * 64.0f + 64.0f;
  float cy = (((float)i1 - 64.0f) * 0.015625f + out1) * 64.0f + 64.0f;
  float cz = (((float)i0 - 64.0f) * 0.015625f + out2) * 64.0f + 64.0f;

  scatter_direct(vol, cx, cy, cz, value);
}

extern "C" void kernel_launch(void* const* d_in, const int* in_sizes, int n_in,
                              void* d_out, int out_size, void* d_ws, size_t ws_size,
                              hipStream_t stream) {
  const int*   inds = (const int*)d_in[0];
  const float* refv = (const float*)d_in[1];
  const float* W0   = (const float*)d_in[2];
  const float* b0   = (const float*)d_in[3];
  const float* W1   = (const float*)d_in[4];
  const float* b1   = (const float*)d_in[5];
  const float* W2   = (const float*)d_in[6];
  const float* b2   = (const float*)d_in[7];
  const float* W3   = (const float*)d_in[8];
  const float* b3   = (const float*)d_in[9];
  const float* W4   = (const float*)d_in[10];
  const float* b4   = (const float*)d_in[11];
  const float* W5   = (const float*)d_in[12];
  const float* b5   = (const float*)d_in[13];

  int N = in_sizes[0] / 3;
  float* vol = (float*)d_out;
  char* w = (char*)d_ws;

  // workspace layout (bytes) — only x8 + partials now (~64.25 KB)
  float* x8       = (float*)(w + 0);     // 8 floats
  float* partials = (float*)(w + 256);   // RED_BLOCKS*8 floats = 64KB

  // k_reduce_w0 zeroes vol in its prologue (hides under W0 fetch)
  k_reduce_w0<<<RED_BLOCKS, 256, 0, stream>>>(inds, W0, partials, (float4*)vol,
                                              3 * N);
  k_mlp<<<1, 256, 0, stream>>>(partials, RED_BLOCKS, b0, W1, b1, W2, b2, W3, b3,
                               W4, b4, x8);
  k_scatter<<<(N + 255) / 256, 256, 0, stream>>>(inds, refv, W5, b5, x8, vol, N);
}